// Round 14
// baseline (553.060 us; speedup 1.0000x reference)
//
#include <hip/hip_runtime.h>
#include <math.h>

#define NN    100000
#define GG    100
#define FIN   12
#define FOUT  32
#define KD    5
#define CC    4
#define EE    1600000
#define ROWS  108          // 9 blocks * 12 features
#define NBF   782          // fwd coarse bins (128 nodes each; last has 96)
#define NBINS 1564         // fwd bins + rev bins
#define NBC   512          // blocks in the coarse build (EE/NBC = 3125 exact)
#define CHUNK 3125
#define NSEG  (NBINS * NBC)   // 800768 per-(chunk,bin) segment bases

// XCD-contiguous chunk remap (R11: contiguous ei/ew reads per XCD).
__device__ __forceinline__ int chunk_of_block(int b) {
    return ((b & 7) << 6) | (b >> 3);      // NBC=512: xcd*64 + seq
}

// ---------------- coarse-bucket CSR build ----------------
// Bin layout: bin_f = dst>>7 in [0,NBF); bin_r = NBF + (src>>7).
// recA is CHUNK-CONTIGUOUS: chunk c owns recA[c*2*CHUNK .. (c+1)*2*CHUNK),
// grouped by bin inside (bases from a block-local scan). Writes land in a
// 50 KB L2-resident window -> ~1x write-back (R10-12 bin-major layout had
// 4.7x write amplification from cross-block 64B-line sharing).
// recA: .x = nbr | (local_node << 17), .y = edge weight.

// P1: histogram own chunk -> local exclusive scan -> global segment bases
// (stored to hist_g[chunk][bin] for consumers) -> place records. No global
// atomics, no separate k_hist, no global scan.
__global__ __launch_bounds__(256) void k_place(const int* __restrict__ ei,
                                               const float* __restrict__ ew,
                                               int* __restrict__ hist_g,
                                               int2* __restrict__ recA) {
    __shared__ int hist[NBINS];
    __shared__ int cur[NBINS];
    __shared__ int sc[256];
    int t = threadIdx.x;
    int chunk = chunk_of_block(blockIdx.x);
    int lo = chunk * CHUNK, hi = lo + CHUNK;
    int chunkBase = chunk * 2 * CHUNK;

    for (int i = t; i < NBINS; i += 256) hist[i] = 0;
    __syncthreads();
    for (int e = lo + t; e < hi; e += 256) {
        int s = ei[e], d = ei[EE + e];
        atomicAdd(&hist[d >> 7], 1);
        atomicAdd(&hist[NBF + (s >> 7)], 1);
    }
    __syncthreads();

    // block-level exclusive scan over hist[0..NBINS): 7 elems/thread + 256-scan
    int tmp[7];
    int run = 0;
#pragma unroll
    for (int k = 0; k < 7; ++k) {
        int idx = t * 7 + k;
        int v = (idx < NBINS) ? hist[idx] : 0;
        tmp[k] = run;
        run += v;
    }
    sc[t] = run;
    __syncthreads();
    for (int d = 1; d < 256; d <<= 1) {
        int x = sc[t];
        if (t >= d) x += sc[t - d];
        __syncthreads();
        sc[t] = x;
        __syncthreads();
    }
    int tb = sc[t] - run;              // exclusive base for this thread's 7 slots
#pragma unroll
    for (int k = 0; k < 7; ++k) {
        int idx = t * 7 + k;
        if (idx < NBINS) cur[idx] = chunkBase + tb + tmp[k];
    }
    __syncthreads();
    for (int i = t; i < NBINS; i += 256)       // segment bases for k_binoff/k_subcsr
        hist_g[chunk * NBINS + i] = cur[i];
    __syncthreads();

    for (int e = lo + t; e < hi; e += 256) {
        int s = ei[e], d = ei[EE + e];
        float w = ew[e];
        int pf = atomicAdd(&cur[d >> 7], 1);
        recA[pf] = make_int2(s | ((d & 127) << 17), __float_as_int(w));
        int pr = atomicAdd(&cur[NBF + (s >> 7)], 1);
        recA[pr] = make_int2(d | ((s & 127) << 17), __float_as_int(w));
    }
}

// P2: bin totals by column-summing segment bases (coalesced: consecutive b
// read consecutive ints). count(c,b) = nextbase - base; chunk end closes b=last.
__global__ void k_binoff(const int* __restrict__ hist_g, int* __restrict__ bincnt) {
    int b = blockIdx.x * 256 + threadIdx.x;
    if (b >= NBINS) return;
    int s = 0;
    for (int c = 0; c < NBC; ++c) {
        int b0 = hist_g[c * NBINS + b];
        int b1 = (b + 1 < NBINS) ? hist_g[c * NBINS + b + 1] : (c + 1) * 2 * CHUNK;
        s += b1 - b0;
    }
    bincnt[b] = s;
}

// P3: one-block exclusive scan of bincnt -> off[0..NBINS]; terminators.
__global__ __launch_bounds__(1024) void k_scanoff(const int* __restrict__ bincnt,
                                                  int* __restrict__ off,
                                                  int* __restrict__ off_node) {
    __shared__ int sh[1024];
    int t = threadIdx.x;
    int a = (2 * t     < NBINS) ? bincnt[2 * t]     : 0;
    int b = (2 * t + 1 < NBINS) ? bincnt[2 * t + 1] : 0;
    int s = a + b;
    sh[t] = s;
    __syncthreads();
    for (int d = 1; d < 1024; d <<= 1) {
        int x = sh[t];
        if (t >= d) x += sh[t - d];
        __syncthreads();
        sh[t] = x;
        __syncthreads();
    }
    int base = sh[t] - s;
    if (2 * t < NBINS)     off[2 * t] = base;
    if (2 * t + 1 < NBINS) off[2 * t + 1] = base + a;
    if (t == 1023) { off[NBINS] = 2 * EE; off_node[2 * NN] = 2 * EE; }
}

// P4: per-bin counting sort by local node -> per-node CSR (4B records, rec2
// bin-contiguous as before), fused degree sums -> dinv, (rev) gA = dinv_out.*x.
// Bin b's records live in 512 scattered segments of recA; segment bases staged
// to LDS once.
__global__ __launch_bounds__(256) void k_subcsr(
        const int* __restrict__ off, const int* __restrict__ hist_g,
        const int2* __restrict__ recA, const float* __restrict__ x,
        int* __restrict__ off_node, int* __restrict__ rec2,
        float* __restrict__ dinv_in, float* __restrict__ dinv_out,
        float* __restrict__ gA) {
    __shared__ int   segA[NBC];
    __shared__ int   segB[NBC];
    __shared__ int   hist[128];
    __shared__ int   lofs[128];
    __shared__ int   cur[128];
    __shared__ float wsum[128];
    __shared__ float dl[128];
    int b = blockIdx.x;
    int t = threadIdx.x;
    if (t < 128) { hist[t] = 0; wsum[t] = 0.f; }
    for (int c = t; c < NBC; c += 256) {
        segA[c] = hist_g[c * NBINS + b];
        segB[c] = (b + 1 < NBINS) ? hist_g[c * NBINS + b + 1] : (c + 1) * 2 * CHUNK;
    }
    __syncthreads();
    for (int c = t; c < NBC; c += 256) {
        for (int e = segA[c]; e < segB[c]; ++e) {
            int2 r = recA[e];
            int loc = r.x >> 17;
            atomicAdd(&hist[loc], 1);
            atomicAdd(&wsum[loc], __int_as_float(r.y));
        }
    }
    __syncthreads();
    if (t < 128) lofs[t] = hist[t];
    __syncthreads();
    for (int d = 1; d < 128; d <<= 1) {
        int v = 0;
        if (t < 128 && t >= d) v = lofs[t - d];
        __syncthreads();
        if (t < 128) lofs[t] += v;
        __syncthreads();
    }
    bool rev = b >= NBF;
    int base = (rev ? b - NBF : b) * 128;
    int e0 = off[b];
    if (t < 128) {
        int ex = lofs[t] - hist[t];      // exclusive
        lofs[t] = ex;
        cur[t] = 0;
        int node = base + t;
        if (node < NN) {
            off_node[(rev ? NN : 0) + node] = e0 + ex;
            float inv = 1.f / wsum[t];
            dl[t] = inv;
            if (rev) dinv_out[node] = inv;
            else     dinv_in[node]  = inv;
        }
    }
    __syncthreads();
    for (int c = t; c < NBC; c += 256) {
        for (int e = segA[c]; e < segB[c]; ++e) {
            int rx = recA[e].x;
            int loc = rx >> 17;
            int pos = e0 + lofs[loc] + atomicAdd(&cur[loc], 1);
            rec2[pos] = rx & 0x1FFFF;
        }
    }
    if (rev) {
        __syncthreads();
        for (int i = t; i < 128 * 3; i += 256) {
            int loc = i / 3, ch = i - loc * 3;
            int node = base + loc;
            if (node < NN) {
                float4 v = *(const float4*)(x + (size_t)node * FIN + ch * 4);
                float sc = dl[loc];
                v.x *= sc; v.y *= sc; v.z *= sc; v.w *= sc;
                *(float4*)(gA + (size_t)node * FIN + ch * 4) = v;
            }
        }
    }
}

// ---------------- weights ----------------

// Collapse W[2,K,44,32] -> effective [108,32] (only first 12 input rows matter;
// block 0 = W[0,0]+W[1,0]; blocks 1..4 = W[0,k]; blocks 5..8 = W[1,k]).
__global__ void k_buildw(const float* __restrict__ Wz_in, const float* __restrict__ Wh_in,
                         float* __restrict__ Wz, float* __restrict__ Wh) {
    int t = blockIdx.x * 256 + threadIdx.x;
    if (t >= 2 * ROWS * FOUT) return;
    int sel = t / (ROWS * FOUT);
    int rem = t - sel * ROWS * FOUT;
    int r = rem / FOUT;
    int f = rem - r * FOUT;
    int b = r / 12;
    int i = r - b * 12;
    const float* Ws = sel ? Wh_in : Wz_in;
    float v;
    if (b == 0)
        v = Ws[(0 * KD + 0) * 44 * 32 + i * 32 + f] + Ws[(1 * KD + 0) * 44 * 32 + i * 32 + f];
    else if (b <= 4)
        v = Ws[(0 * KD + b) * 44 * 32 + i * 32 + f];
    else
        v = Ws[(1 * KD + (b - 4)) * 44 * 32 + i * 32 + f];
    (sel ? Wh : Wz)[r * FOUT + f] = v;
}

// ---------------- diffusion gather (R12 row-major form) ----------------
// ROW-MAJOR arrays: lanes 3k..3k+2 read the same 48B row -> wave coalescer
// merges them (R13's chunk-major split broke this: FETCH 187 MB, 2.2x slower).
// XCD-partitioned by direction: blocks (blockIdx&7) 0-3 fwd, 4-7 rev.
// fwd: out[n] = c * sum gIn[src]              - prevF[n];  gOut[n] = dinv_out[n]*out[n]
// rev: out[n] = c * dinv_in[n] * sum hIn[dst] - prevR[n]
__global__ __launch_bounds__(256) void k_gather(
        const int* __restrict__ off_node, const int* __restrict__ rec2,
        const float* __restrict__ gIn, const float* __restrict__ hIn,
        const float* __restrict__ prevF, const float* __restrict__ prevR,
        const float* __restrict__ dinv_in, const float* __restrict__ dinv_out,
        float* __restrict__ outF, float* __restrict__ outR,
        float* __restrict__ gOut, float c) {
    int xcd = blockIdx.x & 7;
    int grp = blockIdx.x >> 3;             // 0..292
    bool rev = xcd >= 4;
    int lin = (grp * 4 + (xcd & 3)) * 256 + threadIdx.x;
    if (lin >= 3 * NN) return;
    int node = lin / 3;
    int ch = lin - node * 3;
    int i0 = (rev ? NN : 0) + node;
    int e0 = off_node[i0], e1 = off_node[i0 + 1];
    const float* in = rev ? hIn : gIn;

    float ax = 0.f, ay = 0.f, az = 0.f, aw = 0.f;
    float bx = 0.f, by = 0.f, bz = 0.f, bw = 0.f;
    int e = e0;
    for (; e + 3 < e1; e += 4) {
        int n0 = rec2[e], n1 = rec2[e + 1], n2 = rec2[e + 2], n3 = rec2[e + 3];
        float4 v0 = *(const float4*)(in + (size_t)n0 * FIN + ch * 4);
        float4 v1 = *(const float4*)(in + (size_t)n1 * FIN + ch * 4);
        float4 v2 = *(const float4*)(in + (size_t)n2 * FIN + ch * 4);
        float4 v3 = *(const float4*)(in + (size_t)n3 * FIN + ch * 4);
        ax += v0.x; ay += v0.y; az += v0.z; aw += v0.w;
        bx += v1.x; by += v1.y; bz += v1.z; bw += v1.w;
        ax += v2.x; ay += v2.y; az += v2.z; aw += v2.w;
        bx += v3.x; by += v3.y; bz += v3.z; bw += v3.w;
    }
    for (; e < e1; ++e) {
        int n0 = rec2[e];
        float4 v0 = *(const float4*)(in + (size_t)n0 * FIN + ch * 4);
        ax += v0.x; ay += v0.y; az += v0.z; aw += v0.w;
    }
    ax += bx; ay += by; az += bz; aw += bw;

    float sc = rev ? c * dinv_in[node] : c;
    ax *= sc; ay *= sc; az *= sc; aw *= sc;

    size_t o = (size_t)node * FIN + ch * 4;
    if (prevF) {
        float4 p = *(const float4*)((rev ? prevR : prevF) + o);
        ax -= p.x; ay -= p.y; az -= p.z; aw -= p.w;
    }
    float4 res = make_float4(ax, ay, az, aw);
    *(float4*)((rev ? outR : outF) + o) = res;
    if (!rev && gOut) {
        float g = dinv_out[node];
        res.x *= g; res.y *= g; res.z *= g; res.w *= g;
        *(float4*)(gOut + o) = res;
    }
}

// ---------------- epilogue ----------------

__global__ void k_init_out(float* __restrict__ out, const float* __restrict__ b_lin) {
    int t = blockIdx.x * 256 + threadIdx.x;
    if (t < GG * CC) out[t] = b_lin[t & 3];
}

// Wave-level feature split + LDS row staging (R12 form, row-major TS).
__global__ __launch_bounds__(256) void k_fused(
        const float* __restrict__ x, const float* __restrict__ TS,
        const float* __restrict__ Wz, const float* __restrict__ Wh,
        const float* __restrict__ bz, const float* __restrict__ bh,
        const float* __restrict__ Wlin, float* __restrict__ out) {
    __shared__ float rows[128][13];
    __shared__ float red[256 * CC];
    int g = blockIdx.x >> 3;
    int seg = blockIdx.x & 7;
    int base = g * 1000 + seg * 125;
    int tid = threadIdx.x;
    int lane = tid & 63;
    int wave = tid >> 6;
    int f0 = __builtin_amdgcn_readfirstlane(wave * 8);   // wave-uniform f-quarter

    float az0[8], ah0[8], az1[8], ah1[8];
#pragma unroll
    for (int fi = 0; fi < 8; ++fi) {
        float vz = bz[f0 + fi], vh = bh[f0 + fi];
        az0[fi] = vz; ah0[fi] = vh; az1[fi] = vz; ah1[fi] = vh;
    }
    bool act1 = (lane + 64) < 125;     // second node valid for lanes 0..60

    for (int b = 0; b < 9; ++b) {
        const float* src = (b == 0) ? (x + (size_t)base * FIN)
                                    : (TS + ((size_t)(b - 1) * NN + base) * FIN);
        __syncthreads();               // protect rows[] from prior-iter readers
        for (int q = tid; q < 375; q += 256) {    // 125*12 floats = 375 float4
            float4 v = *(const float4*)(src + q * 4);
            int e = q * 4;
            int n0 = e / 12,       i0 = e - n0 * 12;       rows[n0][i0] = v.x;
            int n1 = (e + 1) / 12, i1 = (e + 1) - n1 * 12; rows[n1][i1] = v.y;
            int n2 = (e + 2) / 12, i2 = (e + 2) - n2 * 12; rows[n2][i2] = v.z;
            int n3 = (e + 3) / 12, i3 = (e + 3) - n3 * 12; rows[n3][i3] = v.w;
        }
        __syncthreads();
        const float* wzr = Wz + b * 12 * FOUT + f0;
        const float* whr = Wh + b * 12 * FOUT + f0;
#pragma unroll
        for (int i = 0; i < FIN; ++i) {
            float v0 = rows[lane][i];
            float v1 = rows[lane + 64][i];   // in-bounds (<=127); masked later
#pragma unroll
            for (int fi = 0; fi < 8; ++fi) {
                float wz = wzr[i * FOUT + fi];   // scalar loads (wave-uniform addr)
                float wh = whr[i * FOUT + fi];
                az0[fi] = fmaf(v0, wz, az0[fi]);
                az1[fi] = fmaf(v1, wz, az1[fi]);
                ah0[fi] = fmaf(v0, wh, ah0[fi]);
                ah1[fi] = fmaf(v1, wh, ah1[fi]);
            }
        }
    }

    float o[CC] = {0.f, 0.f, 0.f, 0.f};
#pragma unroll
    for (int fi = 0; fi < 8; ++fi) {
        float z = 1.f / (1.f + __expf(-az0[fi]));
        float e2 = __expf(2.f * ah0[fi]);
        float th = 1.f - 2.f / (e2 + 1.f);
        float hv = fmaxf((1.f - z) * th, 0.f);
#pragma unroll
        for (int c = 0; c < CC; ++c) o[c] = fmaf(hv, Wlin[(f0 + fi) * 4 + c], o[c]);
    }
    if (act1) {
#pragma unroll
        for (int fi = 0; fi < 8; ++fi) {
            float z = 1.f / (1.f + __expf(-az1[fi]));
            float e2 = __expf(2.f * ah1[fi]);
            float th = 1.f - 2.f / (e2 + 1.f);
            float hv = fmaxf((1.f - z) * th, 0.f);
#pragma unroll
            for (int c = 0; c < CC; ++c) o[c] = fmaf(hv, Wlin[(f0 + fi) * 4 + c], o[c]);
        }
    }

#pragma unroll
    for (int c = 0; c < CC; ++c) red[tid * CC + c] = o[c];
    __syncthreads();
    for (int st = 128; st > 0; st >>= 1) {
        if (tid < st) {
#pragma unroll
            for (int c = 0; c < CC; ++c) red[tid * CC + c] += red[(tid + st) * CC + c];
        }
        __syncthreads();
    }
    if (tid == 0) {
#pragma unroll
        for (int c = 0; c < CC; ++c) atomicAdd(out + g * CC + c, red[c] * 0.001f);
    }
}

// ---------------- launch ----------------

extern "C" void kernel_launch(void* const* d_in, const int* in_sizes, int n_in,
                              void* d_out, int out_size, void* d_ws, size_t ws_size,
                              hipStream_t stream) {
    const float* x     = (const float*)d_in[0];
    const int*   ei    = (const int*)d_in[1];
    const float* ew    = (const float*)d_in[2];
    // d_in[3] (batch) unused: graphs are exactly 1000 contiguous nodes
    const float* W_z   = (const float*)d_in[4];
    const float* b_z   = (const float*)d_in[5];
    // d_in[6], d_in[7] (W_r, b_r) unused: R only multiplies the zero hidden state
    const float* W_h   = (const float*)d_in[8];
    const float* b_h   = (const float*)d_in[9];
    const float* W_lin = (const float*)d_in[10];
    const float* b_lin = (const float*)d_in[11];
    float* out = (float*)d_out;

    // ---- workspace layout (~66.5 MB; hist_g NOT aliased: alive thru k_subcsr) ----
    int*   rec2     = (int*)d_ws;                       // 2*EE ints (12.8 MB)
    float* TS       = (float*)(rec2 + 2 * (size_t)EE);  // 8*N*12 floats (38.4 MB)
    int2*  recA     = (int2*)TS;                        // ALIAS: 2*EE int2, dead before gather 1
    float* gA       = TS + (size_t)8 * NN * FIN;        // N*12 (4.8 MB) shadow buffers
    float* gB       = gA + (size_t)NN * FIN;            // N*12
    float* dinv_in  = gB + (size_t)NN * FIN;            // N
    float* dinv_out = dinv_in + NN;                     // N
    float* Wz       = dinv_out + NN;                    // 108*32
    float* Wh       = Wz + ROWS * FOUT;                 // 108*32
    int*   off      = (int*)(Wh + ROWS * FOUT);         // NBINS+1
    int*   off_node = off + NBINS + 1;                  // 2N+1
    int*   hist_g   = off_node + 2 * NN + 1;            // NSEG (3.2 MB) segment bases
    int*   bincnt   = hist_g + NSEG;                    // NBINS

    float* T1o = TS + (size_t)0 * NN * FIN;
    float* T2o = TS + (size_t)1 * NN * FIN;
    float* T3o = TS + (size_t)2 * NN * FIN;
    float* T4o = TS + (size_t)3 * NN * FIN;
    float* T1i = TS + (size_t)4 * NN * FIN;
    float* T2i = TS + (size_t)5 * NN * FIN;
    float* T3i = TS + (size_t)6 * NN * FIN;
    float* T4i = TS + (size_t)7 * NN * FIN;

    dim3 B(256);
    int nbG = 2344;                            // 293 * 8 — exact for the XCD swizzle

    k_place<<<NBC, B, 0, stream>>>(ei, ew, hist_g, recA);
    k_binoff<<<(NBINS + 255) / 256, B, 0, stream>>>(hist_g, bincnt);
    k_scanoff<<<1, 1024, 0, stream>>>(bincnt, off, off_node);
    k_subcsr<<<NBINS, B, 0, stream>>>(off, hist_g, recA, x, off_node, rec2,
                                      dinv_in, dinv_out, gA);

    k_buildw<<<(2 * ROWS * FOUT + 255) / 256, B, 0, stream>>>(W_z, W_h, Wz, Wh);

    // Chebyshev diffusion basis: per-node gather, pre-scaled fwd inputs (gA/gB)
    k_gather<<<nbG, B, 0, stream>>>(off_node, rec2, gA, x,   nullptr, nullptr, dinv_in, dinv_out, T1o, T1i, gB, 1.f);
    k_gather<<<nbG, B, 0, stream>>>(off_node, rec2, gB, T1i, x,       x,       dinv_in, dinv_out, T2o, T2i, gA, 2.f);
    k_gather<<<nbG, B, 0, stream>>>(off_node, rec2, gA, T2i, T1o,     T1i,     dinv_in, dinv_out, T3o, T3i, gB, 2.f);
    k_gather<<<nbG, B, 0, stream>>>(off_node, rec2, gB, T3i, T2o,     T2i,     dinv_in, dinv_out, T4o, T4i, nullptr, 2.f);

    k_init_out<<<(GG * CC + 255) / 256, B, 0, stream>>>(out, b_lin);
    k_fused<<<8 * GG, B, 0, stream>>>(x, TS, Wz, Wh, b_z, b_h, W_lin, out);
}

// Round 15
// 347.381 us; speedup vs baseline: 1.5921x; 1.5921x over previous
//
#include <hip/hip_runtime.h>
#include <math.h>

#define NN    100000
#define GG    100
#define FIN   12
#define FOUT  32
#define KD    5
#define CC    4
#define EE    1600000
#define ROWS  108          // 9 blocks * 12 features
#define NBF   782          // fwd coarse bins (128 nodes each; last has 96)
#define NBINS 1564         // fwd bins + rev bins
#define NBC   1024         // blocks in the coarse build (CHUNK=1563, last=1051)
#define CHUNK 1563
#define NSEG  (NBINS * NBC)   // 1601536 = 1564 * 1024 exactly

// XCD-contiguous chunk remap (R11: contiguous ei/ew reads per XCD).
__device__ __forceinline__ int chunk_of_block(int b) {
    return ((b & 7) << 7) | (b >> 3);      // NBC=1024: xcd*128 + seq
}

// ---------------- coarse-bucket CSR build (R12 structure) ----------------
// Bin layout: bin_f = dst>>7 in [0,NBF); bin_r = NBF + (src>>7).
// recA (bin-major): .x = nbr | (local_node << 17), .y = edge weight.

// P1: per-block LDS histogram -> stores into bin-major hist_g[bin][chunk].
__global__ __launch_bounds__(256) void k_hist(const int* __restrict__ ei,
                                              int* __restrict__ hist_g) {
    __shared__ int hist[NBINS];
    for (int i = threadIdx.x; i < NBINS; i += 256) hist[i] = 0;
    __syncthreads();
    int chunk = chunk_of_block(blockIdx.x);
    int lo = chunk * CHUNK, hi = lo + CHUNK;
    if (hi > EE) hi = EE;
    for (int e = lo + threadIdx.x; e < hi; e += 256) {
        int s = ei[e], d = ei[EE + e];
        atomicAdd(&hist[d >> 7], 1);
        atomicAdd(&hist[NBF + (s >> 7)], 1);
    }
    __syncthreads();
    for (int i = threadIdx.x; i < NBINS; i += 256)
        hist_g[i * NBC + chunk] = hist[i];
}

// P2: 3-kernel exclusive scan of hist_g[0..NSEG) in place -> per-(bin,chunk) bases.
__global__ __launch_bounds__(1024) void k_scan1(int* __restrict__ g,
                                                int* __restrict__ bsum) {
    __shared__ int sh[1024];
    int t = threadIdx.x;
    int i = blockIdx.x * 1024 + t;
    int v = g[i];                      // NSEG is an exact multiple of 1024
    sh[t] = v;
    __syncthreads();
    for (int d = 1; d < 1024; d <<= 1) {
        int x = sh[t];
        if (t >= d) x += sh[t - d];
        __syncthreads();
        sh[t] = x;
        __syncthreads();
    }
    g[i] = sh[t] - v;
    if (t == 1023) bsum[blockIdx.x] = sh[1023];
}

// scan of nb<=2048 block sums, 2 elems/thread (nb = 1564 here).
__global__ __launch_bounds__(1024) void k_scan2(int* __restrict__ bsum, int nb) {
    __shared__ int sh[1024];
    int t = threadIdx.x;
    int a = (2 * t     < nb) ? bsum[2 * t]     : 0;
    int b = (2 * t + 1 < nb) ? bsum[2 * t + 1] : 0;
    int s = a + b;
    sh[t] = s;
    __syncthreads();
    for (int d = 1; d < 1024; d <<= 1) {
        int x = sh[t];
        if (t >= d) x += sh[t - d];
        __syncthreads();
        sh[t] = x;
        __syncthreads();
    }
    int base = sh[t] - s;
    if (2 * t < nb)     bsum[2 * t] = base;
    if (2 * t + 1 < nb) bsum[2 * t + 1] = base + a;
}

// adds block base; extracts bucket offsets off[bin] = scanned[bin*NBC];
// terminates off/off_node with the constant total 2*EE.
__global__ __launch_bounds__(1024) void k_scan3(int* __restrict__ g,
                                                const int* __restrict__ bsum,
                                                int* __restrict__ off,
                                                int* __restrict__ off_node) {
    int i = blockIdx.x * 1024 + threadIdx.x;
    int v = g[i] + bsum[blockIdx.x];
    g[i] = v;
    if ((i & (NBC - 1)) == 0) off[i / NBC] = v;
    if (i == 0) { off[NBINS] = 2 * EE; off_node[2 * NN] = 2 * EE; }
}

// P3: seed LDS cursors from precomputed bases, place records (bin-major recA).
__global__ __launch_bounds__(256) void k_place(const int* __restrict__ ei,
                                               const float* __restrict__ ew,
                                               const int* __restrict__ base_g,
                                               int2* __restrict__ recA) {
    __shared__ int cur[NBINS];
    int chunk = chunk_of_block(blockIdx.x);
    for (int i = threadIdx.x; i < NBINS; i += 256) cur[i] = base_g[i * NBC + chunk];
    __syncthreads();
    int lo = chunk * CHUNK, hi = lo + CHUNK;
    if (hi > EE) hi = EE;
    for (int e = lo + threadIdx.x; e < hi; e += 256) {
        int s = ei[e], d = ei[EE + e];
        float w = ew[e];
        int pf = atomicAdd(&cur[d >> 7], 1);
        recA[pf] = make_int2(s | ((d & 127) << 17), __float_as_int(w));
        int pr = atomicAdd(&cur[NBF + (s >> 7)], 1);
        recA[pr] = make_int2(d | ((s & 127) << 17), __float_as_int(w));
    }
}

// P4: per-bin counting sort by local node -> exact per-node CSR (4B records),
// fused weighted-degree sums -> dinv, and (rev bins) gA = dinv_out .* x.
__global__ __launch_bounds__(256) void k_subcsr(
        const int* __restrict__ off, const int2* __restrict__ recA,
        const float* __restrict__ x,
        int* __restrict__ off_node, int* __restrict__ rec2,
        float* __restrict__ dinv_in, float* __restrict__ dinv_out,
        float* __restrict__ gA) {
    __shared__ int   hist[128];
    __shared__ int   lofs[128];
    __shared__ int   cur[128];
    __shared__ float wsum[128];
    __shared__ float dl[128];
    int b = blockIdx.x;
    int t = threadIdx.x;
    if (t < 128) { hist[t] = 0; wsum[t] = 0.f; }
    __syncthreads();
    int e0 = off[b], e1 = off[b + 1];
    for (int e = e0 + t; e < e1; e += 256) {
        int2 r = recA[e];
        int loc = r.x >> 17;
        atomicAdd(&hist[loc], 1);
        atomicAdd(&wsum[loc], __int_as_float(r.y));
    }
    __syncthreads();
    if (t < 128) lofs[t] = hist[t];
    __syncthreads();
    for (int d = 1; d < 128; d <<= 1) {
        int v = 0;
        if (t < 128 && t >= d) v = lofs[t - d];
        __syncthreads();
        if (t < 128) lofs[t] += v;
        __syncthreads();
    }
    bool rev = b >= NBF;
    int base = (rev ? b - NBF : b) * 128;
    if (t < 128) {
        int ex = lofs[t] - hist[t];      // exclusive
        lofs[t] = ex;
        cur[t] = 0;
        int node = base + t;
        if (node < NN) {
            off_node[(rev ? NN : 0) + node] = e0 + ex;
            float inv = 1.f / wsum[t];
            dl[t] = inv;
            if (rev) dinv_out[node] = inv;
            else     dinv_in[node]  = inv;
        }
    }
    __syncthreads();
    for (int e = e0 + t; e < e1; e += 256) {
        int rx = recA[e].x;
        int loc = rx >> 17;
        int pos = e0 + lofs[loc] + atomicAdd(&cur[loc], 1);
        rec2[pos] = rx & 0x1FFFF;
    }
    if (rev) {
        __syncthreads();
        for (int i = t; i < 128 * 3; i += 256) {
            int loc = i / 3, ch = i - loc * 3;
            int node = base + loc;
            if (node < NN) {
                float4 v = *(const float4*)(x + (size_t)node * FIN + ch * 4);
                float sc = dl[loc];
                v.x *= sc; v.y *= sc; v.z *= sc; v.w *= sc;
                *(float4*)(gA + (size_t)node * FIN + ch * 4) = v;
            }
        }
    }
}

// ---------------- weights ----------------

// Collapse W[2,K,44,32] -> effective [108,32] (only first 12 input rows matter;
// block 0 = W[0,0]+W[1,0]; blocks 1..4 = W[0,k]; blocks 5..8 = W[1,k]).
__global__ void k_buildw(const float* __restrict__ Wz_in, const float* __restrict__ Wh_in,
                         float* __restrict__ Wz, float* __restrict__ Wh) {
    int t = blockIdx.x * 256 + threadIdx.x;
    if (t >= 2 * ROWS * FOUT) return;
    int sel = t / (ROWS * FOUT);
    int rem = t - sel * ROWS * FOUT;
    int r = rem / FOUT;
    int f = rem - r * FOUT;
    int b = r / 12;
    int i = r - b * 12;
    const float* Ws = sel ? Wh_in : Wz_in;
    float v;
    if (b == 0)
        v = Ws[(0 * KD + 0) * 44 * 32 + i * 32 + f] + Ws[(1 * KD + 0) * 44 * 32 + i * 32 + f];
    else if (b <= 4)
        v = Ws[(0 * KD + b) * 44 * 32 + i * 32 + f];
    else
        v = Ws[(1 * KD + (b - 4)) * 44 * 32 + i * 32 + f];
    (sel ? Wh : Wz)[r * FOUT + f] = v;
}

// ---------------- diffusion gather ----------------
// ROW-MAJOR arrays (R13 lesson: lanes 3k..3k+2 share a 48B row -> wave
// coalescer merges the fetch; chunk-major broke this). XCD direction split:
// blocks (blockIdx&7) 0-3 fwd, 4-7 rev. NEW: the block's rec2 window is one
// CONTIGUOUS run (rec2 is node-sorted; block covers ~86 consecutive nodes) —
// stage it into LDS coalesced ONCE, killing the 3x redundant scattered
// per-thread rec2 reads. LREC=6144 ints (24KB); window avg ~1365, >130 sigma
// margin; global-read fallback kept for safety.
#define LREC 6144
__global__ __launch_bounds__(256) void k_gather(
        const int* __restrict__ off_node, const int* __restrict__ rec2,
        const float* __restrict__ gIn, const float* __restrict__ hIn,
        const float* __restrict__ prevF, const float* __restrict__ prevR,
        const float* __restrict__ dinv_in, const float* __restrict__ dinv_out,
        float* __restrict__ outF, float* __restrict__ outR,
        float* __restrict__ gOut, float c) {
    __shared__ int lrec[LREC];
    int xcd = blockIdx.x & 7;
    int grp = blockIdx.x >> 3;             // 0..292
    bool rev = xcd >= 4;
    int dbase = rev ? NN : 0;
    int ub = (grp * 4 + (xcd & 3)) * 256;  // block's first lin
    int lin = ub + threadIdx.x;

    // block's contiguous rec2 window
    int u1 = ub + 255; if (u1 > 3 * NN - 1) u1 = 3 * NN - 1;
    int node0 = ub / 3, node1 = u1 / 3;
    int w0 = off_node[dbase + node0];
    int w1 = off_node[dbase + node1 + 1];
    int wn = w1 - w0;
    bool useLds = (wn <= LREC);
    if (useLds) {
        for (int i = threadIdx.x; i < wn; i += 256) lrec[i] = rec2[w0 + i];
    }
    __syncthreads();

    if (lin < 3 * NN) {
        int node = lin / 3;
        int ch = lin - node * 3;
        int i0 = dbase + node;
        int e0 = off_node[i0], e1 = off_node[i0 + 1];
        const float* in = rev ? hIn : gIn;

        float ax = 0.f, ay = 0.f, az = 0.f, aw = 0.f;
        float bx = 0.f, by = 0.f, bz = 0.f, bw = 0.f;
        if (useLds) {
            int a0 = e0 - w0, a1 = e1 - w0;
            int e = a0;
            for (; e + 3 < a1; e += 4) {
                int n0 = lrec[e], n1 = lrec[e + 1], n2 = lrec[e + 2], n3 = lrec[e + 3];
                float4 v0 = *(const float4*)(in + (size_t)n0 * FIN + ch * 4);
                float4 v1 = *(const float4*)(in + (size_t)n1 * FIN + ch * 4);
                float4 v2 = *(const float4*)(in + (size_t)n2 * FIN + ch * 4);
                float4 v3 = *(const float4*)(in + (size_t)n3 * FIN + ch * 4);
                ax += v0.x; ay += v0.y; az += v0.z; aw += v0.w;
                bx += v1.x; by += v1.y; bz += v1.z; bw += v1.w;
                ax += v2.x; ay += v2.y; az += v2.z; aw += v2.w;
                bx += v3.x; by += v3.y; bz += v3.z; bw += v3.w;
            }
            for (; e < a1; ++e) {
                int n0 = lrec[e];
                float4 v0 = *(const float4*)(in + (size_t)n0 * FIN + ch * 4);
                ax += v0.x; ay += v0.y; az += v0.z; aw += v0.w;
            }
        } else {
            int e = e0;
            for (; e + 3 < e1; e += 4) {
                int n0 = rec2[e], n1 = rec2[e + 1], n2 = rec2[e + 2], n3 = rec2[e + 3];
                float4 v0 = *(const float4*)(in + (size_t)n0 * FIN + ch * 4);
                float4 v1 = *(const float4*)(in + (size_t)n1 * FIN + ch * 4);
                float4 v2 = *(const float4*)(in + (size_t)n2 * FIN + ch * 4);
                float4 v3 = *(const float4*)(in + (size_t)n3 * FIN + ch * 4);
                ax += v0.x; ay += v0.y; az += v0.z; aw += v0.w;
                bx += v1.x; by += v1.y; bz += v1.z; bw += v1.w;
                ax += v2.x; ay += v2.y; az += v2.z; aw += v2.w;
                bx += v3.x; by += v3.y; bz += v3.z; bw += v3.w;
            }
            for (; e < e1; ++e) {
                int n0 = rec2[e];
                float4 v0 = *(const float4*)(in + (size_t)n0 * FIN + ch * 4);
                ax += v0.x; ay += v0.y; az += v0.z; aw += v0.w;
            }
        }
        ax += bx; ay += by; az += bz; aw += bw;

        float sc = rev ? c * dinv_in[node] : c;
        ax *= sc; ay *= sc; az *= sc; aw *= sc;

        size_t o = (size_t)node * FIN + ch * 4;
        if (prevF) {
            float4 p = *(const float4*)((rev ? prevR : prevF) + o);
            ax -= p.x; ay -= p.y; az -= p.z; aw -= p.w;
        }
        float4 res = make_float4(ax, ay, az, aw);
        *(float4*)((rev ? outR : outF) + o) = res;
        if (!rev && gOut) {
            float g = dinv_out[node];
            res.x *= g; res.y *= g; res.z *= g; res.w *= g;
            *(float4*)(gOut + o) = res;
        }
    }
}

// ---------------- epilogue ----------------

__global__ void k_init_out(float* __restrict__ out, const float* __restrict__ b_lin) {
    int t = blockIdx.x * 256 + threadIdx.x;
    if (t < GG * CC) out[t] = b_lin[t & 3];
}

// Wave-level feature split + LDS row staging (R12 form, row-major TS).
__global__ __launch_bounds__(256) void k_fused(
        const float* __restrict__ x, const float* __restrict__ TS,
        const float* __restrict__ Wz, const float* __restrict__ Wh,
        const float* __restrict__ bz, const float* __restrict__ bh,
        const float* __restrict__ Wlin, float* __restrict__ out) {
    __shared__ float rows[128][13];
    __shared__ float red[256 * CC];
    int g = blockIdx.x >> 3;
    int seg = blockIdx.x & 7;
    int base = g * 1000 + seg * 125;
    int tid = threadIdx.x;
    int lane = tid & 63;
    int wave = tid >> 6;
    int f0 = __builtin_amdgcn_readfirstlane(wave * 8);   // wave-uniform f-quarter

    float az0[8], ah0[8], az1[8], ah1[8];
#pragma unroll
    for (int fi = 0; fi < 8; ++fi) {
        float vz = bz[f0 + fi], vh = bh[f0 + fi];
        az0[fi] = vz; ah0[fi] = vh; az1[fi] = vz; ah1[fi] = vh;
    }
    bool act1 = (lane + 64) < 125;     // second node valid for lanes 0..60

    for (int b = 0; b < 9; ++b) {
        const float* src = (b == 0) ? (x + (size_t)base * FIN)
                                    : (TS + ((size_t)(b - 1) * NN + base) * FIN);
        __syncthreads();               // protect rows[] from prior-iter readers
        for (int q = tid; q < 375; q += 256) {    // 125*12 floats = 375 float4
            float4 v = *(const float4*)(src + q * 4);
            int e = q * 4;
            int n0 = e / 12,       i0 = e - n0 * 12;       rows[n0][i0] = v.x;
            int n1 = (e + 1) / 12, i1 = (e + 1) - n1 * 12; rows[n1][i1] = v.y;
            int n2 = (e + 2) / 12, i2 = (e + 2) - n2 * 12; rows[n2][i2] = v.z;
            int n3 = (e + 3) / 12, i3 = (e + 3) - n3 * 12; rows[n3][i3] = v.w;
        }
        __syncthreads();
        const float* wzr = Wz + b * 12 * FOUT + f0;
        const float* whr = Wh + b * 12 * FOUT + f0;
#pragma unroll
        for (int i = 0; i < FIN; ++i) {
            float v0 = rows[lane][i];
            float v1 = rows[lane + 64][i];   // in-bounds (<=127); masked later
#pragma unroll
            for (int fi = 0; fi < 8; ++fi) {
                float wz = wzr[i * FOUT + fi];   // scalar loads (wave-uniform addr)
                float wh = whr[i * FOUT + fi];
                az0[fi] = fmaf(v0, wz, az0[fi]);
                az1[fi] = fmaf(v1, wz, az1[fi]);
                ah0[fi] = fmaf(v0, wh, ah0[fi]);
                ah1[fi] = fmaf(v1, wh, ah1[fi]);
            }
        }
    }

    float o[CC] = {0.f, 0.f, 0.f, 0.f};
#pragma unroll
    for (int fi = 0; fi < 8; ++fi) {
        float z = 1.f / (1.f + __expf(-az0[fi]));
        float e2 = __expf(2.f * ah0[fi]);
        float th = 1.f - 2.f / (e2 + 1.f);
        float hv = fmaxf((1.f - z) * th, 0.f);
#pragma unroll
        for (int c = 0; c < CC; ++c) o[c] = fmaf(hv, Wlin[(f0 + fi) * 4 + c], o[c]);
    }
    if (act1) {
#pragma unroll
        for (int fi = 0; fi < 8; ++fi) {
            float z = 1.f / (1.f + __expf(-az1[fi]));
            float e2 = __expf(2.f * ah1[fi]);
            float th = 1.f - 2.f / (e2 + 1.f);
            float hv = fmaxf((1.f - z) * th, 0.f);
#pragma unroll
            for (int c = 0; c < CC; ++c) o[c] = fmaf(hv, Wlin[(f0 + fi) * 4 + c], o[c]);
        }
    }

#pragma unroll
    for (int c = 0; c < CC; ++c) red[tid * CC + c] = o[c];
    __syncthreads();
    for (int st = 128; st > 0; st >>= 1) {
        if (tid < st) {
#pragma unroll
            for (int c = 0; c < CC; ++c) red[tid * CC + c] += red[(tid + st) * CC + c];
        }
        __syncthreads();
    }
    if (tid == 0) {
#pragma unroll
        for (int c = 0; c < CC; ++c) atomicAdd(out + g * CC + c, red[c] * 0.001f);
    }
}

// ---------------- launch ----------------

extern "C" void kernel_launch(void* const* d_in, const int* in_sizes, int n_in,
                              void* d_out, int out_size, void* d_ws, size_t ws_size,
                              hipStream_t stream) {
    const float* x     = (const float*)d_in[0];
    const int*   ei    = (const int*)d_in[1];
    const float* ew    = (const float*)d_in[2];
    // d_in[3] (batch) unused: graphs are exactly 1000 contiguous nodes
    const float* W_z   = (const float*)d_in[4];
    const float* b_z   = (const float*)d_in[5];
    // d_in[6], d_in[7] (W_r, b_r) unused: R only multiplies the zero hidden state
    const float* W_h   = (const float*)d_in[8];
    const float* b_h   = (const float*)d_in[9];
    const float* W_lin = (const float*)d_in[10];
    const float* b_lin = (const float*)d_in[11];
    float* out = (float*)d_out;

    // ---- workspace layout (~62.7 MB) ----
    int*   rec2     = (int*)d_ws;                       // 2*EE ints (12.8 MB)
    float* TS       = (float*)(rec2 + 2 * (size_t)EE);  // 8*N*12 floats (38.4 MB)
    int2*  recA     = (int2*)TS;                        // ALIAS: 2*EE int2, dead before gather 1
    int*   hist_g   = rec2;                             // ALIAS: NSEG ints (6.4 MB), dead before k_subcsr writes rec2
    int*   bsumS    = rec2 + NSEG;                      // ALIAS: NSEG/1024 = 1564 ints
    float* gA       = TS + (size_t)8 * NN * FIN;        // N*12 (4.8 MB) shadow buffers
    float* gB       = gA + (size_t)NN * FIN;            // N*12
    float* dinv_in  = gB + (size_t)NN * FIN;            // N
    float* dinv_out = dinv_in + NN;                     // N
    float* Wz       = dinv_out + NN;                    // 108*32
    float* Wh       = Wz + ROWS * FOUT;                 // 108*32
    int*   off      = (int*)(Wh + ROWS * FOUT);         // NBINS+1
    int*   off_node = off + NBINS + 1;                  // 2N+1

    float* T1o = TS + (size_t)0 * NN * FIN;
    float* T2o = TS + (size_t)1 * NN * FIN;
    float* T3o = TS + (size_t)2 * NN * FIN;
    float* T4o = TS + (size_t)3 * NN * FIN;
    float* T1i = TS + (size_t)4 * NN * FIN;
    float* T2i = TS + (size_t)5 * NN * FIN;
    float* T3i = TS + (size_t)6 * NN * FIN;
    float* T4i = TS + (size_t)7 * NN * FIN;

    dim3 B(256);
    int nbG = 2344;                            // 293 * 8 — exact for the XCD swizzle
    int nbScan = NSEG / 1024;                  // 1564, exact

    k_hist<<<NBC, B, 0, stream>>>(ei, hist_g);
    k_scan1<<<nbScan, 1024, 0, stream>>>(hist_g, bsumS);
    k_scan2<<<1, 1024, 0, stream>>>(bsumS, nbScan);
    k_scan3<<<nbScan, 1024, 0, stream>>>(hist_g, bsumS, off, off_node);
    k_place<<<NBC, B, 0, stream>>>(ei, ew, hist_g, recA);
    k_subcsr<<<NBINS, B, 0, stream>>>(off, recA, x, off_node, rec2, dinv_in, dinv_out, gA);

    k_buildw<<<(2 * ROWS * FOUT + 255) / 256, B, 0, stream>>>(W_z, W_h, Wz, Wh);

    // Chebyshev diffusion basis: per-node gather (LDS-staged rec2), pre-scaled
    // fwd inputs (gA/gB)
    k_gather<<<nbG, B, 0, stream>>>(off_node, rec2, gA, x,   nullptr, nullptr, dinv_in, dinv_out, T1o, T1i, gB, 1.f);
    k_gather<<<nbG, B, 0, stream>>>(off_node, rec2, gB, T1i, x,       x,       dinv_in, dinv_out, T2o, T2i, gA, 2.f);
    k_gather<<<nbG, B, 0, stream>>>(off_node, rec2, gA, T2i, T1o,     T1i,     dinv_in, dinv_out, T3o, T3i, gB, 2.f);
    k_gather<<<nbG, B, 0, stream>>>(off_node, rec2, gB, T3i, T2o,     T2i,     dinv_in, dinv_out, T4o, T4i, nullptr, 2.f);

    k_init_out<<<(GG * CC + 255) / 256, B, 0, stream>>>(out, b_lin);
    k_fused<<<8 * GG, B, 0, stream>>>(x, TS, Wz, Wh, b_z, b_h, W_lin, out);
}

// Round 16
// 344.394 us; speedup vs baseline: 1.6059x; 1.0087x over previous
//
#include <hip/hip_runtime.h>
#include <math.h>

#define NN    100000
#define GG    100
#define FIN   12
#define FOUT  32
#define KD    5
#define CC    4
#define EE    1600000
#define ROWS  108          // 9 blocks * 12 features
#define NBF   782          // fwd coarse bins (128 nodes each; last has 96)
#define NBINS 1564         // fwd bins + rev bins
#define NBC   1024         // blocks in the coarse build (CHUNK=1563, last=1051)
#define CHUNK 1563
#define NSEG  (NBINS * NBC)   // 1601536 = 1564 * 1024 exactly

// XCD-contiguous chunk remap (R11: contiguous ei/ew reads per XCD).
__device__ __forceinline__ int chunk_of_block(int b) {
    return ((b & 7) << 7) | (b >> 3);      // NBC=1024: xcd*128 + seq
}

// ---------------- coarse-bucket CSR build (R12/R15 structure) ----------------
// Bin layout: bin_f = dst>>7 in [0,NBF); bin_r = NBF + (src>>7).
// recA (bin-major): .x = nbr | (local_node << 17), .y = edge weight.

// P1: per-block LDS histogram -> stores into bin-major hist_g[bin][chunk].
__global__ __launch_bounds__(256) void k_hist(const int* __restrict__ ei,
                                              int* __restrict__ hist_g) {
    __shared__ int hist[NBINS];
    for (int i = threadIdx.x; i < NBINS; i += 256) hist[i] = 0;
    __syncthreads();
    int chunk = chunk_of_block(blockIdx.x);
    int lo = chunk * CHUNK, hi = lo + CHUNK;
    if (hi > EE) hi = EE;
    for (int e = lo + threadIdx.x; e < hi; e += 256) {
        int s = ei[e], d = ei[EE + e];
        atomicAdd(&hist[d >> 7], 1);
        atomicAdd(&hist[NBF + (s >> 7)], 1);
    }
    __syncthreads();
    for (int i = threadIdx.x; i < NBINS; i += 256)
        hist_g[i * NBC + blockIdx.x == 0 ? i * NBC + chunk : i * NBC + chunk] = hist[i];
}

// P2: 3-kernel exclusive scan of hist_g[0..NSEG) in place -> per-(bin,chunk) bases.
__global__ __launch_bounds__(1024) void k_scan1(int* __restrict__ g,
                                                int* __restrict__ bsum) {
    __shared__ int sh[1024];
    int t = threadIdx.x;
    int i = blockIdx.x * 1024 + t;
    int v = g[i];                      // NSEG is an exact multiple of 1024
    sh[t] = v;
    __syncthreads();
    for (int d = 1; d < 1024; d <<= 1) {
        int x = sh[t];
        if (t >= d) x += sh[t - d];
        __syncthreads();
        sh[t] = x;
        __syncthreads();
    }
    g[i] = sh[t] - v;
    if (t == 1023) bsum[blockIdx.x] = sh[1023];
}

// scan of nb<=2048 block sums, 2 elems/thread (nb = 1564 here).
__global__ __launch_bounds__(1024) void k_scan2(int* __restrict__ bsum, int nb) {
    __shared__ int sh[1024];
    int t = threadIdx.x;
    int a = (2 * t     < nb) ? bsum[2 * t]     : 0;
    int b = (2 * t + 1 < nb) ? bsum[2 * t + 1] : 0;
    int s = a + b;
    sh[t] = s;
    __syncthreads();
    for (int d = 1; d < 1024; d <<= 1) {
        int x = sh[t];
        if (t >= d) x += sh[t - d];
        __syncthreads();
        sh[t] = x;
        __syncthreads();
    }
    int base = sh[t] - s;
    if (2 * t < nb)     bsum[2 * t] = base;
    if (2 * t + 1 < nb) bsum[2 * t + 1] = base + a;
}

// adds block base; extracts bucket offsets off[bin] = scanned[bin*NBC];
// terminates off/off_node with the constant total 2*EE.
__global__ __launch_bounds__(1024) void k_scan3(int* __restrict__ g,
                                                const int* __restrict__ bsum,
                                                int* __restrict__ off,
                                                int* __restrict__ off_node) {
    int i = blockIdx.x * 1024 + threadIdx.x;
    int v = g[i] + bsum[blockIdx.x];
    g[i] = v;
    if ((i & (NBC - 1)) == 0) off[i / NBC] = v;
    if (i == 0) { off[NBINS] = 2 * EE; off_node[2 * NN] = 2 * EE; }
}

// P3: seed LDS cursors from precomputed bases, place records (bin-major recA).
__global__ __launch_bounds__(256) void k_place(const int* __restrict__ ei,
                                               const float* __restrict__ ew,
                                               const int* __restrict__ base_g,
                                               int2* __restrict__ recA) {
    __shared__ int cur[NBINS];
    int chunk = chunk_of_block(blockIdx.x);
    for (int i = threadIdx.x; i < NBINS; i += 256) cur[i] = base_g[i * NBC + chunk];
    __syncthreads();
    int lo = chunk * CHUNK, hi = lo + CHUNK;
    if (hi > EE) hi = EE;
    for (int e = lo + threadIdx.x; e < hi; e += 256) {
        int s = ei[e], d = ei[EE + e];
        float w = ew[e];
        int pf = atomicAdd(&cur[d >> 7], 1);
        recA[pf] = make_int2(s | ((d & 127) << 17), __float_as_int(w));
        int pr = atomicAdd(&cur[NBF + (s >> 7)], 1);
        recA[pr] = make_int2(d | ((s & 127) << 17), __float_as_int(w));
    }
}

// P4: per-bin counting sort by local node -> exact per-node CSR (4B records),
// fused weighted-degree sums -> dinv, and (rev bins) gA = dinv_out .* x.
__global__ __launch_bounds__(256) void k_subcsr(
        const int* __restrict__ off, const int2* __restrict__ recA,
        const float* __restrict__ x,
        int* __restrict__ off_node, int* __restrict__ rec2,
        float* __restrict__ dinv_in, float* __restrict__ dinv_out,
        float* __restrict__ gA) {
    __shared__ int   hist[128];
    __shared__ int   lofs[128];
    __shared__ int   cur[128];
    __shared__ float wsum[128];
    __shared__ float dl[128];
    int b = blockIdx.x;
    int t = threadIdx.x;
    if (t < 128) { hist[t] = 0; wsum[t] = 0.f; }
    __syncthreads();
    int e0 = off[b], e1 = off[b + 1];
    for (int e = e0 + t; e < e1; e += 256) {
        int2 r = recA[e];
        int loc = r.x >> 17;
        atomicAdd(&hist[loc], 1);
        atomicAdd(&wsum[loc], __int_as_float(r.y));
    }
    __syncthreads();
    if (t < 128) lofs[t] = hist[t];
    __syncthreads();
    for (int d = 1; d < 128; d <<= 1) {
        int v = 0;
        if (t < 128 && t >= d) v = lofs[t - d];
        __syncthreads();
        if (t < 128) lofs[t] += v;
        __syncthreads();
    }
    bool rev = b >= NBF;
    int base = (rev ? b - NBF : b) * 128;
    if (t < 128) {
        int ex = lofs[t] - hist[t];      // exclusive
        lofs[t] = ex;
        cur[t] = 0;
        int node = base + t;
        if (node < NN) {
            off_node[(rev ? NN : 0) + node] = e0 + ex;
            float inv = 1.f / wsum[t];
            dl[t] = inv;
            if (rev) dinv_out[node] = inv;
            else     dinv_in[node]  = inv;
        }
    }
    __syncthreads();
    for (int e = e0 + t; e < e1; e += 256) {
        int rx = recA[e].x;
        int loc = rx >> 17;
        int pos = e0 + lofs[loc] + atomicAdd(&cur[loc], 1);
        rec2[pos] = rx & 0x1FFFF;
    }
    if (rev) {
        __syncthreads();
        for (int i = t; i < 128 * 3; i += 256) {
            int loc = i / 3, ch = i - loc * 3;
            int node = base + loc;
            if (node < NN) {
                float4 v = *(const float4*)(x + (size_t)node * FIN + ch * 4);
                float sc = dl[loc];
                v.x *= sc; v.y *= sc; v.z *= sc; v.w *= sc;
                *(float4*)(gA + (size_t)node * FIN + ch * 4) = v;
            }
        }
    }
}

// ---------------- weights + output init (merged) ----------------

// Collapse W[2,K,44,32] -> effective [108,32]; also seed out with b_lin.
__global__ void k_misc(const float* __restrict__ Wz_in, const float* __restrict__ Wh_in,
                       float* __restrict__ Wz, float* __restrict__ Wh,
                       const float* __restrict__ b_lin, float* __restrict__ out) {
    int t = blockIdx.x * 256 + threadIdx.x;
    if (t < 2 * ROWS * FOUT) {
        int sel = t / (ROWS * FOUT);
        int rem = t - sel * ROWS * FOUT;
        int r = rem / FOUT;
        int f = rem - r * FOUT;
        int b = r / 12;
        int i = r - b * 12;
        const float* Ws = sel ? Wh_in : Wz_in;
        float v;
        if (b == 0)
            v = Ws[(0 * KD + 0) * 44 * 32 + i * 32 + f] + Ws[(1 * KD + 0) * 44 * 32 + i * 32 + f];
        else if (b <= 4)
            v = Ws[(0 * KD + b) * 44 * 32 + i * 32 + f];
        else
            v = Ws[(1 * KD + (b - 4)) * 44 * 32 + i * 32 + f];
        (sel ? Wh : Wz)[r * FOUT + f] = v;
    }
    int u = t - 2 * ROWS * FOUT;
    if (u >= 0 && u < GG * CC) out[u] = b_lin[u & 3];
}

// ---------------- diffusion gather ----------------
// ROW-MAJOR arrays (R13 lesson: lanes 3k..3k+2 share a 48B row -> wave
// coalescer merges the fetch). XCD direction split: (blockIdx&7) 0-3 fwd,
// 4-7 rev. rec2 window staged to LDS coalesced (R15). LREC=2048 (8KB: lifts
// the R15 24KB LDS occupancy cap 6->10+ blocks/CU; window mean 1376, +18
// sigma margin; global fallback kept). 8-wide unrolled edge loop: 8
// independent row loads in flight per iteration (R15 was 4).
#define LREC 2048
__global__ __launch_bounds__(256) void k_gather(
        const int* __restrict__ off_node, const int* __restrict__ rec2,
        const float* __restrict__ gIn, const float* __restrict__ hIn,
        const float* __restrict__ prevF, const float* __restrict__ prevR,
        const float* __restrict__ dinv_in, const float* __restrict__ dinv_out,
        float* __restrict__ outF, float* __restrict__ outR,
        float* __restrict__ gOut, float c) {
    __shared__ int lrec[LREC];
    int xcd = blockIdx.x & 7;
    int grp = blockIdx.x >> 3;             // 0..292
    bool rev = xcd >= 4;
    int dbase = rev ? NN : 0;
    int ub = (grp * 4 + (xcd & 3)) * 256;  // block's first lin
    int lin = ub + threadIdx.x;

    // block's contiguous rec2 window
    int u1 = ub + 255; if (u1 > 3 * NN - 1) u1 = 3 * NN - 1;
    int node0 = ub / 3, node1 = u1 / 3;
    int w0 = off_node[dbase + node0];
    int w1 = off_node[dbase + node1 + 1];
    int wn = w1 - w0;
    bool useLds = (wn <= LREC);
    if (useLds) {
        for (int i = threadIdx.x; i < wn; i += 256) lrec[i] = rec2[w0 + i];
    }
    __syncthreads();

    if (lin < 3 * NN) {
        int node = lin / 3;
        int ch = lin - node * 3;
        int i0 = dbase + node;
        int e0 = off_node[i0], e1 = off_node[i0 + 1];
        const float* in = rev ? hIn : gIn;

        float ax = 0.f, ay = 0.f, az = 0.f, aw = 0.f;
        float bx = 0.f, by = 0.f, bz = 0.f, bw = 0.f;
        if (useLds) {
            int a0 = e0 - w0, a1 = e1 - w0;
            int e = a0;
            for (; e + 7 < a1; e += 8) {
                int n0 = lrec[e],     n1 = lrec[e + 1], n2 = lrec[e + 2], n3 = lrec[e + 3];
                int n4 = lrec[e + 4], n5 = lrec[e + 5], n6 = lrec[e + 6], n7 = lrec[e + 7];
                float4 v0 = *(const float4*)(in + (size_t)n0 * FIN + ch * 4);
                float4 v1 = *(const float4*)(in + (size_t)n1 * FIN + ch * 4);
                float4 v2 = *(const float4*)(in + (size_t)n2 * FIN + ch * 4);
                float4 v3 = *(const float4*)(in + (size_t)n3 * FIN + ch * 4);
                float4 v4 = *(const float4*)(in + (size_t)n4 * FIN + ch * 4);
                float4 v5 = *(const float4*)(in + (size_t)n5 * FIN + ch * 4);
                float4 v6 = *(const float4*)(in + (size_t)n6 * FIN + ch * 4);
                float4 v7 = *(const float4*)(in + (size_t)n7 * FIN + ch * 4);
                ax += v0.x; ay += v0.y; az += v0.z; aw += v0.w;
                bx += v1.x; by += v1.y; bz += v1.z; bw += v1.w;
                ax += v2.x; ay += v2.y; az += v2.z; aw += v2.w;
                bx += v3.x; by += v3.y; bz += v3.z; bw += v3.w;
                ax += v4.x; ay += v4.y; az += v4.z; aw += v4.w;
                bx += v5.x; by += v5.y; bz += v5.z; bw += v5.w;
                ax += v6.x; ay += v6.y; az += v6.z; aw += v6.w;
                bx += v7.x; by += v7.y; bz += v7.z; bw += v7.w;
            }
            for (; e < a1; ++e) {
                int n0 = lrec[e];
                float4 v0 = *(const float4*)(in + (size_t)n0 * FIN + ch * 4);
                ax += v0.x; ay += v0.y; az += v0.z; aw += v0.w;
            }
        } else {
            int e = e0;
            for (; e + 3 < e1; e += 4) {
                int n0 = rec2[e], n1 = rec2[e + 1], n2 = rec2[e + 2], n3 = rec2[e + 3];
                float4 v0 = *(const float4*)(in + (size_t)n0 * FIN + ch * 4);
                float4 v1 = *(const float4*)(in + (size_t)n1 * FIN + ch * 4);
                float4 v2 = *(const float4*)(in + (size_t)n2 * FIN + ch * 4);
                float4 v3 = *(const float4*)(in + (size_t)n3 * FIN + ch * 4);
                ax += v0.x; ay += v0.y; az += v0.z; aw += v0.w;
                bx += v1.x; by += v1.y; bz += v1.z; bw += v1.w;
                ax += v2.x; ay += v2.y; az += v2.z; aw += v2.w;
                bx += v3.x; by += v3.y; bz += v3.z; bw += v3.w;
            }
            for (; e < e1; ++e) {
                int n0 = rec2[e];
                float4 v0 = *(const float4*)(in + (size_t)n0 * FIN + ch * 4);
                ax += v0.x; ay += v0.y; az += v0.z; aw += v0.w;
            }
        }
        ax += bx; ay += by; az += bz; aw += bw;

        float sc = rev ? c * dinv_in[node] : c;
        ax *= sc; ay *= sc; az *= sc; aw *= sc;

        size_t o = (size_t)node * FIN + ch * 4;
        if (prevF) {
            float4 p = *(const float4*)((rev ? prevR : prevF) + o);
            ax -= p.x; ay -= p.y; az -= p.z; aw -= p.w;
        }
        float4 res = make_float4(ax, ay, az, aw);
        *(float4*)((rev ? outR : outF) + o) = res;
        if (!rev && gOut) {
            float g = dinv_out[node];
            res.x *= g; res.y *= g; res.z *= g; res.w *= g;
            *(float4*)(gOut + o) = res;
        }
    }
}

// ---------------- epilogue ----------------

// Wave-level feature split + LDS row staging (R12 form, row-major TS).
__global__ __launch_bounds__(256) void k_fused(
        const float* __restrict__ x, const float* __restrict__ TS,
        const float* __restrict__ Wz, const float* __restrict__ Wh,
        const float* __restrict__ bz, const float* __restrict__ bh,
        const float* __restrict__ Wlin, float* __restrict__ out) {
    __shared__ float rows[128][13];
    __shared__ float red[256 * CC];
    int g = blockIdx.x >> 3;
    int seg = blockIdx.x & 7;
    int base = g * 1000 + seg * 125;
    int tid = threadIdx.x;
    int lane = tid & 63;
    int wave = tid >> 6;
    int f0 = __builtin_amdgcn_readfirstlane(wave * 8);   // wave-uniform f-quarter

    float az0[8], ah0[8], az1[8], ah1[8];
#pragma unroll
    for (int fi = 0; fi < 8; ++fi) {
        float vz = bz[f0 + fi], vh = bh[f0 + fi];
        az0[fi] = vz; ah0[fi] = vh; az1[fi] = vz; ah1[fi] = vh;
    }
    bool act1 = (lane + 64) < 125;     // second node valid for lanes 0..60

    for (int b = 0; b < 9; ++b) {
        const float* src = (b == 0) ? (x + (size_t)base * FIN)
                                    : (TS + ((size_t)(b - 1) * NN + base) * FIN);
        __syncthreads();               // protect rows[] from prior-iter readers
        for (int q = tid; q < 375; q += 256) {    // 125*12 floats = 375 float4
            float4 v = *(const float4*)(src + q * 4);
            int e = q * 4;
            int n0 = e / 12,       i0 = e - n0 * 12;       rows[n0][i0] = v.x;
            int n1 = (e + 1) / 12, i1 = (e + 1) - n1 * 12; rows[n1][i1] = v.y;
            int n2 = (e + 2) / 12, i2 = (e + 2) - n2 * 12; rows[n2][i2] = v.z;
            int n3 = (e + 3) / 12, i3 = (e + 3) - n3 * 12; rows[n3][i3] = v.w;
        }
        __syncthreads();
        const float* wzr = Wz + b * 12 * FOUT + f0;
        const float* whr = Wh + b * 12 * FOUT + f0;
#pragma unroll
        for (int i = 0; i < FIN; ++i) {
            float v0 = rows[lane][i];
            float v1 = rows[lane + 64][i];   // in-bounds (<=127); masked later
#pragma unroll
            for (int fi = 0; fi < 8; ++fi) {
                float wz = wzr[i * FOUT + fi];   // scalar loads (wave-uniform addr)
                float wh = whr[i * FOUT + fi];
                az0[fi] = fmaf(v0, wz, az0[fi]);
                az1[fi] = fmaf(v1, wz, az1[fi]);
                ah0[fi] = fmaf(v0, wh, ah0[fi]);
                ah1[fi] = fmaf(v1, wh, ah1[fi]);
            }
        }
    }

    float o[CC] = {0.f, 0.f, 0.f, 0.f};
#pragma unroll
    for (int fi = 0; fi < 8; ++fi) {
        float z = 1.f / (1.f + __expf(-az0[fi]));
        float e2 = __expf(2.f * ah0[fi]);
        float th = 1.f - 2.f / (e2 + 1.f);
        float hv = fmaxf((1.f - z) * th, 0.f);
#pragma unroll
        for (int c = 0; c < CC; ++c) o[c] = fmaf(hv, Wlin[(f0 + fi) * 4 + c], o[c]);
    }
    if (act1) {
#pragma unroll
        for (int fi = 0; fi < 8; ++fi) {
            float z = 1.f / (1.f + __expf(-az1[fi]));
            float e2 = __expf(2.f * ah1[fi]);
            float th = 1.f - 2.f / (e2 + 1.f);
            float hv = fmaxf((1.f - z) * th, 0.f);
#pragma unroll
            for (int c = 0; c < CC; ++c) o[c] = fmaf(hv, Wlin[(f0 + fi) * 4 + c], o[c]);
        }
    }

#pragma unroll
    for (int c = 0; c < CC; ++c) red[tid * CC + c] = o[c];
    __syncthreads();
    for (int st = 128; st > 0; st >>= 1) {
        if (tid < st) {
#pragma unroll
            for (int c = 0; c < CC; ++c) red[tid * CC + c] += red[(tid + st) * CC + c];
        }
        __syncthreads();
    }
    if (tid == 0) {
#pragma unroll
        for (int c = 0; c < CC; ++c) atomicAdd(out + g * CC + c, red[c] * 0.001f);
    }
}

// ---------------- launch ----------------

extern "C" void kernel_launch(void* const* d_in, const int* in_sizes, int n_in,
                              void* d_out, int out_size, void* d_ws, size_t ws_size,
                              hipStream_t stream) {
    const float* x     = (const float*)d_in[0];
    const int*   ei    = (const int*)d_in[1];
    const float* ew    = (const float*)d_in[2];
    // d_in[3] (batch) unused: graphs are exactly 1000 contiguous nodes
    const float* W_z   = (const float*)d_in[4];
    const float* b_z   = (const float*)d_in[5];
    // d_in[6], d_in[7] (W_r, b_r) unused: R only multiplies the zero hidden state
    const float* W_h   = (const float*)d_in[8];
    const float* b_h   = (const float*)d_in[9];
    const float* W_lin = (const float*)d_in[10];
    const float* b_lin = (const float*)d_in[11];
    float* out = (float*)d_out;

    // ---- workspace layout (~62.7 MB) ----
    int*   rec2     = (int*)d_ws;                       // 2*EE ints (12.8 MB)
    float* TS       = (float*)(rec2 + 2 * (size_t)EE);  // 8*N*12 floats (38.4 MB)
    int2*  recA     = (int2*)TS;                        // ALIAS: 2*EE int2, dead before gather 1
    int*   hist_g   = rec2;                             // ALIAS: NSEG ints (6.4 MB), dead before k_subcsr writes rec2
    int*   bsumS    = rec2 + NSEG;                      // ALIAS: NSEG/1024 = 1564 ints
    float* gA       = TS + (size_t)8 * NN * FIN;        // N*12 (4.8 MB) shadow buffers
    float* gB       = gA + (size_t)NN * FIN;            // N*12
    float* dinv_in  = gB + (size_t)NN * FIN;            // N
    float* dinv_out = dinv_in + NN;                     // N
    float* Wz       = dinv_out + NN;                    // 108*32
    float* Wh       = Wz + ROWS * FOUT;                 // 108*32
    int*   off      = (int*)(Wh + ROWS * FOUT);         // NBINS+1
    int*   off_node = off + NBINS + 1;                  // 2N+1

    float* T1o = TS + (size_t)0 * NN * FIN;
    float* T2o = TS + (size_t)1 * NN * FIN;
    float* T3o = TS + (size_t)2 * NN * FIN;
    float* T4o = TS + (size_t)3 * NN * FIN;
    float* T1i = TS + (size_t)4 * NN * FIN;
    float* T2i = TS + (size_t)5 * NN * FIN;
    float* T3i = TS + (size_t)6 * NN * FIN;
    float* T4i = TS + (size_t)7 * NN * FIN;

    dim3 B(256);
    int nbG = 2344;                            // 293 * 8 — exact for the XCD swizzle
    int nbScan = NSEG / 1024;                  // 1564, exact

    k_hist<<<NBC, B, 0, stream>>>(ei, hist_g);
    k_scan1<<<nbScan, 1024, 0, stream>>>(hist_g, bsumS);
    k_scan2<<<1, 1024, 0, stream>>>(bsumS, nbScan);
    k_scan3<<<nbScan, 1024, 0, stream>>>(hist_g, bsumS, off, off_node);
    k_place<<<NBC, B, 0, stream>>>(ei, ew, hist_g, recA);
    k_subcsr<<<NBINS, B, 0, stream>>>(off, recA, x, off_node, rec2, dinv_in, dinv_out, gA);

    k_misc<<<(2 * ROWS * FOUT + GG * CC + 255) / 256, B, 0, stream>>>(W_z, W_h, Wz, Wh, b_lin, out);

    // Chebyshev diffusion basis: per-node gather (LDS-staged rec2), pre-scaled
    // fwd inputs (gA/gB)
    k_gather<<<nbG, B, 0, stream>>>(off_node, rec2, gA, x,   nullptr, nullptr, dinv_in, dinv_out, T1o, T1i, gB, 1.f);
    k_gather<<<nbG, B, 0, stream>>>(off_node, rec2, gB, T1i, x,       x,       dinv_in, dinv_out, T2o, T2i, gA, 2.f);
    k_gather<<<nbG, B, 0, stream>>>(off_node, rec2, gA, T2i, T1o,     T1i,     dinv_in, dinv_out, T3o, T3i, gB, 2.f);
    k_gather<<<nbG, B, 0, stream>>>(off_node, rec2, gB, T3i, T2o,     T2i,     dinv_in, dinv_out, T4o, T4i, nullptr, 2.f);

    k_fused<<<8 * GG, B, 0, stream>>>(x, TS, Wz, Wh, b_z, b_h, W_lin, out);
}